// Round 7
// baseline (202.077 us; speedup 1.0000x reference)
//
#include <hip/hip_runtime.h>
#include <math.h>

#define A_TOT  36864
#define N_IMG  32
#define M_GT   32
#define TOTAL_K 256
#define MAX_FG_K 128
#define NCHUNK 144          // 256-anchor chunks per image (tail kernels)
#define NCHM   48           // k_main chunks: 768 contiguous anchors, 3 per thread
#define APB    768
#define CAP    1024
#define FGB    32
#define BGB    64
#define RAW_NEG1 ((int)0xBF800000u)   // __float_as_int(-1.0f)
#define RAW_P07  ((int)0x3F333333u)   // __float_as_int(0.7f)
#define RAW_P03  ((int)0x3E99999Au)   // __float_as_int(0.3f)
#define INT_MINV ((int)0x80000000u)
// IoU values live in {-1.0} ∪ [0,1]; signed-int compare of raw float bits ==
// float compare on that domain (no -0.0/NaN on the valid path).
// flags layout: bid[0:4] | fg<<5 | bg<<6 | bin<<7 (10b)
//
// Shape lessons (R2-R6, all HW-measured):
//  - UNROLLED 32-iter loop, UNIFORM j (compile-time LDS offsets, no tie-break:
//    ascending j => vi>beste is exact first-argmax) = 87% VALUBusy form (R2/R5,
//    absmax 0). Staggered-m variant costs ~15% (R6: 71% VALUBusy).
//  - 64-way same-address LDS atomicMax is free (R2/R5 PMC: 0 conflicts).
//  - while(mask)/cull variants serialize on dependent LDS reads: 3x loss.
//  - Wave-capacity quantization: 1536 blocks * 4 waves = 6144 = 0.75 * 8192
//    resident-wave capacity -> single round, no 1-block/CU tail (R5 lesson).
//  - empty-box clamp + merged vm>0 atomic validated bit-exact (R5/R6 absmax 0).
//  - ~57us graph overhead is FIXED and node-count-independent (R1 2 nodes vs
//    R6 6 nodes): extra tiny dispatches are free; only resident time counts.

__device__ __forceinline__ int bin_of(float r){
    int b = (int)(r * 1024.0f);
    return b > 1023 ? 1023 : (b < 0 ? 0 : b);
}

struct Pred { float x1,y1,x2,y2,area; int valid; };

__device__ __forceinline__ Pred mk_pred(float4 a, float4 d){
#pragma clang fp contract(off)
    Pred p;
    float w  = a.z - a.x + 1.0f;
    float h  = a.w - a.y + 1.0f;
    float cx = a.x + 0.5f*w;
    float cy = a.y + 0.5f*h;
    float pcx = d.x*w + cx;
    float pcy = d.y*h + cy;
    float pw = (float)exp((double)d.z) * w;
    float ph = (float)exp((double)d.w) * h;
    p.x1 = pcx - 0.5f*pw;
    p.y1 = pcy - 0.5f*ph;
    p.x2 = pcx + 0.5f*pw;
    p.y2 = pcy + 0.5f*ph;
    p.valid = (p.x1 >= 0.0f) && (p.y1 >= 0.0f) && (p.x2 < 1024.0f) && (p.y2 < 1024.0f);
    p.area  = (p.x2 - p.x1 + 1.0f) * (p.y2 - p.y1 + 1.0f);
    return p;
}

__device__ __forceinline__ float gt_area(float4 g){
#pragma clang fp contract(off)
    return (g.z - g.x + 1.0f) * (g.w - g.y + 1.0f);
}

__device__ __forceinline__ float iou_val(const Pred& p, float gx1, float gy1,
                                         float gx2, float gy2, float ga){
#pragma clang fp contract(off)
    float iw = fminf(p.x2,gx2) - fmaxf(p.x1,gx1) + 1.0f; iw = iw < 0.0f ? 0.0f : iw;
    float ih = fminf(p.y2,gy2) - fmaxf(p.y1,gy1) + 1.0f; ih = ih < 0.0f ? 0.0f : ih;
    float inter = iw * ih;
    float uni = (p.area + ga) - inter;
    float v = inter / uni;
    return p.valid ? v : -1.0f;
}

__device__ __forceinline__ void coeff_fn(float4 a, float4 g, float cf[4]){
#pragma clang fp contract(off)
    float aw = a.z - a.x + 1.0f, ah = a.w - a.y + 1.0f;
    float acx = a.x + 0.5f*aw,  acy = a.y + 0.5f*ah;
    float gw = g.z - g.x + 1.0f, gh = g.w - g.y + 1.0f;
    float gcx = g.x + 0.5f*gw,  gcy = g.y + 0.5f*gh;
    cf[0] = (gcx - acx) / aw;
    cf[1] = (gcy - acy) / ah;
    cf[2] = (float)log((double)(gw / aw));
    cf[3] = (float)log((double)(gh / ah));
}

// ---------- K1: heavy pass, 3 anchors/thread, UNIFORM-j unrolled loop.
// ---------- 1536 blocks * 4 waves = 6144 waves = 0.75 capacity: single round.
// ---------- Flags, hist atomics (hidden), merged vm>0 atomicMax (64-way
// ---------- same-addr: free), pgm over 0xAA poison. -------------------------
__global__ __launch_bounds__(256) void k_main(
        const float* __restrict__ anchors, const float* __restrict__ gt,
        const float* __restrict__ dl, const float* __restrict__ rs,
        int* __restrict__ bmax, int* __restrict__ flagsA,
        int* __restrict__ pgm, int* __restrict__ hist){
#pragma clang fp contract(off)
    int blk = blockIdx.x;
    int n = blk / NCHM, ch = blk % NCHM;
    int tid = threadIdx.x;
    __shared__ float4 sgt[M_GT];
    __shared__ float  sga[M_GT];
    __shared__ int    sbm[M_GT];
    if(tid < M_GT){
        float4 g = ((const float4*)gt)[n*M_GT + tid];
        sgt[tid] = g; sga[tid] = gt_area(g); sbm[tid] = RAW_NEG1;
    }
    __syncthreads();
    int a0 = ch*APB + tid;
    long ia0 = (long)n*A_TOT + a0;
    float4 anc0 = ((const float4*)anchors)[a0];
    float4 anc1 = ((const float4*)anchors)[a0 + 256];
    float4 anc2 = ((const float4*)anchors)[a0 + 512];
    float4 d0   = ((const float4*)dl)[ia0];
    float4 d1   = ((const float4*)dl)[ia0 + 256];
    float4 d2   = ((const float4*)dl)[ia0 + 512];
    float r0 = rs[ia0];            // hoisted: latency hides under IoU loop
    float r1 = rs[ia0 + 256];
    float r2 = rs[ia0 + 512];
    Pred p0 = mk_pred(anc0, d0);
    Pred p1 = mk_pred(anc1, d1);
    Pred p2 = mk_pred(anc2, d2);
    // empty-box clamp (validated R5/R6, absmax 0): invalid => iw<0 => v=+0.0
    // exactly for every gt; downstream outcomes identical to -1 convention.
    if(!p0.valid){ p0.x1 = 2.0e9f; p0.x2 = -2.0e9f; }
    if(!p1.valid){ p1.x1 = 2.0e9f; p1.x2 = -2.0e9f; }
    if(!p2.valid){ p2.x1 = 2.0e9f; p2.x2 = -2.0e9f; }
    int beste0 = INT_MINV, bid0 = 0;
    int beste1 = INT_MINV, bid1 = 0;
    int beste2 = INT_MINV, bid2 = 0;
    #pragma unroll
    for(int j=0;j<M_GT;++j){
        float4 g = sgt[j];                    // uniform j: immediate-offset ds_read
        float ga = sga[j];
        float iw0 = fminf(p0.x2,g.z) - fmaxf(p0.x1,g.x) + 1.0f; iw0 = iw0 < 0.0f ? 0.0f : iw0;
        float ih0 = fminf(p0.y2,g.w) - fmaxf(p0.y1,g.y) + 1.0f; ih0 = ih0 < 0.0f ? 0.0f : ih0;
        float in0 = iw0 * ih0;
        int vi0 = __float_as_int(in0 / ((p0.area + ga) - in0));
        float iw1 = fminf(p1.x2,g.z) - fmaxf(p1.x1,g.x) + 1.0f; iw1 = iw1 < 0.0f ? 0.0f : iw1;
        float ih1 = fminf(p1.y2,g.w) - fmaxf(p1.y1,g.y) + 1.0f; ih1 = ih1 < 0.0f ? 0.0f : ih1;
        float in1 = iw1 * ih1;
        int vi1 = __float_as_int(in1 / ((p1.area + ga) - in1));
        float iw2 = fminf(p2.x2,g.z) - fmaxf(p2.x1,g.x) + 1.0f; iw2 = iw2 < 0.0f ? 0.0f : iw2;
        float ih2 = fminf(p2.y2,g.w) - fmaxf(p2.y1,g.y) + 1.0f; ih2 = ih2 < 0.0f ? 0.0f : ih2;
        float in2 = iw2 * ih2;
        int vi2 = __float_as_int(in2 / ((p2.area + ga) - in2));
        int vm01 = vi0 > vi1 ? vi0 : vi1;
        int vm = vm01 > vi2 ? vm01 : vi2;
        if(vm > 0) atomicMax(&sbm[j], vm);    // 64-way same-addr: free (R2/R5 PMC)
        // ascending j => strict > is exactly first-argmax (no tie-break ops)
        if(vi0 > beste0){ beste0 = vi0; bid0 = j; }
        if(vi1 > beste1){ beste1 = vi1; bid1 = j; }
        if(vi2 > beste2){ beste2 = vi2; bid2 = j; }
    }
    int bin0 = bin_of(r0);
    int bin1 = bin_of(r1);
    int bin2 = bin_of(r2);
    int thrfg0 = (beste0 >= RAW_P07) ? 1 : 0;
    int thrfg1 = (beste1 >= RAW_P07) ? 1 : 0;
    int thrfg2 = (beste2 >= RAW_P07) ? 1 : 0;
    int bg0 = (!thrfg0) & (beste0 < RAW_P03 ? 1 : 0) & p0.valid;
    int bg1 = (!thrfg1) & (beste1 < RAW_P03 ? 1 : 0) & p1.valid;
    int bg2 = (!thrfg2) & (beste2 < RAW_P03 ? 1 : 0) & p2.valid;
    flagsA[ia0]       = bid0 | (thrfg0<<5) | (bg0<<6) | (bin0<<7);
    flagsA[ia0 + 256] = bid1 | (thrfg1<<5) | (bg1<<6) | (bin1<<7);
    flagsA[ia0 + 512] = bid2 | (thrfg2<<5) | (bg2<<6) | (bin2<<7);
    if(thrfg0 | bg0) atomicAdd(&hist[n*2048 + (thrfg0?0:1024) + bin0], 1);
    if(thrfg1 | bg1) atomicAdd(&hist[n*2048 + (thrfg1?0:1024) + bin1], 1);
    if(thrfg2 | bg2) atomicAdd(&hist[n*2048 + (thrfg2?0:1024) + bin2], 1);
    __syncthreads();
    if(tid < M_GT){
        bmax[blk*M_GT + tid] = sbm[tid];
        atomicMax(&pgm[n*M_GT + tid], sbm[tid]);   // poison 0xAAAAAAAA < raw(-1): no init needed
    }
}

// ---------- K2: sparse abox fix. One block per (image, gt); only chunks with
// ---------- bmax==pgm contain achievers. 768-anchor contiguous chunks =>
// ---------- coalesced recompute. Exactly-once hist repair via atomicOr. -----
__global__ void k_fix(const float* __restrict__ anchors, const float* __restrict__ gt,
                      const float* __restrict__ dl, const int* __restrict__ bmax,
                      const int* __restrict__ pgm, int* __restrict__ flagsA,
                      int* __restrict__ hist){
    int n = blockIdx.x >> 5, m = blockIdx.x & 31;
    int tid = threadIdx.x;
    int target = pgm[n*M_GT + m];
    float4 g = ((const float4*)gt)[n*M_GT + m];
    float ga = gt_area(g);
    __shared__ int s_hits[NCHM];
    __shared__ int s_nh;
    if(tid==0) s_nh = 0;
    __syncthreads();
    if(tid < NCHM && bmax[(n*NCHM + tid)*M_GT + m] == target){
        int pos = atomicAdd(&s_nh, 1);
        s_hits[pos] = tid;
    }
    __syncthreads();
    int nh = s_nh;
    for(int h=0; h<nh; ++h){
        int ch = s_hits[h];
        for(int t=tid; t<APB; t+=256){
            int a = ch*APB + t;
            long ia = (long)n*A_TOT + a;
            float4 anc = ((const float4*)anchors)[a];
            float4 d   = ((const float4*)dl)[ia];
            Pred p = mk_pred(anc, d);
            float v = iou_val(p, g.x, g.y, g.z, g.w, ga);
            if(p.valid && __float_as_int(v) == target){
                int old = atomicOr(&flagsA[ia], FGB);
                if(!(old & FGB)){                 // fg transition: repair histogram
                    int bin = (old >> 7) & 1023;
                    atomicAdd(&hist[n*2048 + bin], 1);
                    if(old & BGB) atomicSub(&hist[n*2048 + 1024 + bin], 1);
                }
            }
        }
    }
}

// ---------- K2b: quota once per image (32 blocks; dispatches are free, the
// ---------- 4608-block redundant scan in k_bound was not). Publishes q[4]. ---
__global__ __launch_bounds__(256) void k_quota(const int* __restrict__ hist,
                                               int* __restrict__ q){
    int n = blockIdx.x, tid = threadIdx.x;
    __shared__ int s_scan[256];
    __shared__ int s_q[4];
    int fgK = 0;
    for(int phase=0; phase<2; ++phase){
        int b0 = 1023 - 4*tid;                              // bins b0..b0-3 desc
        int4 h4 = *(const int4*)&hist[n*2048 + phase*1024 + b0 - 3];
        int part = h4.x + h4.y + h4.z + h4.w;
        s_scan[tid] = part;
        __syncthreads();
        for(int off=1; off<256; off<<=1){
            int add = (tid>=off) ? s_scan[tid-off] : 0;
            __syncthreads();
            s_scan[tid] += add;
            __syncthreads();
        }
        int total = s_scan[255];
        if(tid==0){ s_q[phase*2] = -1; s_q[phase*2+1] = 0; }
        __syncthreads();
        int quota = (phase==0) ? MAX_FG_K : (TOTAL_K - fgK);
        if(total > quota){
            int pre = s_scan[tid] - part, cum = pre;
            int hs4[4] = {h4.w, h4.z, h4.y, h4.x};          // descending bin order
            for(int j=0;j<4;++j){
                int hh = hs4[j];
                if(cum < quota && cum + hh >= quota){ s_q[phase*2] = b0-j; s_q[phase*2+1] = quota-cum; }
                cum += hh;
            }
        }
        __syncthreads();
        if(phase==0) fgK = (total < MAX_FG_K) ? total : MAX_FG_K;
    }
    if(tid < 4) q[n*4 + tid] = s_q[tid];
}

// ---------- K3: sure-keeps, boundary candidates, chunk counts (reads q). ----
__global__ void k_bound(const int* __restrict__ flagsA, const float* __restrict__ rs,
                        const int* __restrict__ q,
                        unsigned long long* __restrict__ cand, int* __restrict__ candcnt,
                        int* __restrict__ chunkcnt){
    int blk = blockIdx.x, tid = threadIdx.x;
    int n = blk / NCHUNK, ch = blk % NCHUNK;
    int wave = tid >> 6, lane = tid & 63;
    __shared__ int s_wc[4];
    int bs0 = q[n*4+0], bs1 = q[n*4+2];
    int a = ch*256 + tid;
    long ia = (long)n*A_TOT + a;
    int f = flagsA[ia];
    int fg = (f>>5)&1;
    int bg = ((f>>6)&1) & !fg;
    int bin = (f>>7)&1023;
    int sure = 0;
    if(fg | bg){
        int c = fg ? 0 : 1;
        int bsel = fg ? bs0 : bs1;
        if(bin > bsel) sure = 1;                 // keepAll encoded as bsel=-1
        else if(bin == bsel){
            int pos = atomicAdd(&candcnt[n*2+c], 1);
            if(pos < CAP){
                // key: (r desc, index asc); r>=0 so raw bits order as uint
                cand[(n*2+c)*CAP + pos] =
                    (((unsigned long long)__float_as_uint(rs[ia]))<<32) | (unsigned)(A_TOT - a);
            }
        }
    }
    unsigned long long mk = __ballot(sure);
    if(lane==0) s_wc[wave] = __popcll(mk);
    __syncthreads();
    if(tid==0) chunkcnt[n*NCHUNK + ch] = s_wc[0]+s_wc[1]+s_wc[2]+s_wc[3];
}

// ---------- K4: merged rank+emit (validated R2/R6). Each of 4608 blocks
// ---------- redundantly ranks the tiny L2-hot candidate list (O(c^2)),
// ---------- accumulates extras per chunk in LDS, inline 144-chunk prefix,
// ---------- ballot-compacts its own chunk. ch==0 writes defaults >= T. ------
__global__ __launch_bounds__(256) void k_out(const float* __restrict__ anchors,
        const float* __restrict__ gt, const int* __restrict__ flagsA,
        const int* __restrict__ q, const int* __restrict__ candcnt,
        const unsigned long long* __restrict__ cand,
        const int* __restrict__ chunkcnt, float* __restrict__ out){
    int blk = blockIdx.x, tid = threadIdx.x;
    int n = blk / NCHUNK, ch = blk % NCHUNK;
    int wave = tid >> 6, lane = tid & 63;
    __shared__ unsigned long long s_ckey[CAP];   // 8 KB, reused per class
    __shared__ int s_scan[256];
    __shared__ int s_cex[NCHUNK];                // rank-keep extras per chunk
    __shared__ unsigned int s_keep[8];           // own-chunk keep bits
    __shared__ int s_wc[4];
    for(int i=tid; i<NCHUNK; i+=256) s_cex[i] = 0;
    if(tid < 8) s_keep[tid] = 0u;
    int bs0 = q[n*4+0], bs1 = q[n*4+2];
    int tk[2] = { q[n*4+1], q[n*4+3] };
    __syncthreads();
    // ---- redundant rank of boundary candidates (deterministic: same data) ----
    for(int c=0; c<2; ++c){
        int take = tk[c];
        if(take == 0) continue;                  // no boundary => no candidates used
        int cc = candcnt[n*2+c]; if(cc > CAP) cc = CAP;
        for(int i=tid; i<cc; i+=256) s_ckey[i] = cand[(n*2+c)*CAP + i];
        __syncthreads();
        for(int i=tid; i<cc; i+=256){
            unsigned long long ki = s_ckey[i];
            int rank = 0;
            for(int j=0;j<cc;++j) rank += (s_ckey[j] > ki) ? 1 : 0;
            if(rank < take){
                int ai = A_TOT - (int)(ki & 0xffffffffu);
                atomicAdd(&s_cex[ai>>8], 1);
                if((ai>>8) == ch) atomicOr(&s_keep[(ai&255)>>5], 1u << (ai & 31));
            }
        }
        __syncthreads();
    }
    // ---- chunk-base prefix (144 L2-hot ints + LDS extras) ----
    int v = (tid < NCHUNK) ? chunkcnt[n*NCHUNK + tid] + s_cex[tid] : 0;
    s_scan[tid] = v;
    __syncthreads();
    for(int off=1; off<256; off<<=1){
        int add = (tid>=off) ? s_scan[tid-off] : 0;
        __syncthreads();
        s_scan[tid] += add;
        __syncthreads();
    }
    int T = s_scan[255];                          // total kept (<= 256)
    int base = (ch > 0) ? s_scan[ch-1] : 0;
    // ---- emit own chunk ----
    int a = ch*256 + tid;
    long ia = (long)n*A_TOT + a;
    int f = flagsA[ia];
    int fg = (f>>5)&1;
    int bg = ((f>>6)&1) & !fg;
    int bin = (f>>7)&1023;
    int bit = (int)((s_keep[tid>>5] >> (tid&31)) & 1u);
    int kept = 0;
    if(fg)      kept = (bin > bs0) || bit;
    else if(bg) kept = (bin > bs1) || bit;
    unsigned long long mk = __ballot(kept);
    if(lane==0) s_wc[wave] = __popcll(mk);
    __syncthreads();
    if(kept){
        int slot = base;
        for(int w=0; w<wave; ++w) slot += s_wc[w];
        slot += __popcll(mk & ((1ull<<lane)-1ull));
        if(slot < TOTAL_K){
            out[n*TOTAL_K + slot] = (float)a;
            out[(long)N_IMG*TOTAL_K + n*TOTAL_K + slot] = fg ? 1.0f : 0.0f;
            float4 aa = ((const float4*)anchors)[a];
            float4 gg = ((const float4*)gt)[n*M_GT + (f & 31)];
            float cf[4]; coeff_fn(aa, gg, cf);
            for(int k=0;k<4;++k)
                out[(long)2*N_IMG*TOTAL_K + ((long)n*TOTAL_K + slot)*4 + k] = cf[k];
        }
    }
    // ---- defaults: padding slots [T,256) behave like anchor 0 (reference
    // ---- zero-init scatter). Disjoint from all emission slots (<T). ----
    if(ch == 0 && tid >= T){
        int m0 = flagsA[(long)n*A_TOT];           // post-fix (no flag writes here)
        int fg0 = (m0>>5)&1, bin0 = (m0>>7)&1023;
        int k0b = (int)(s_keep[0] & 1u);          // only matters when fg0 set
        float fgdef = (fg0 && ((bin0 > bs0) || k0b)) ? 1.0f : 0.0f;
        float4 a0 = ((const float4*)anchors)[0];
        float4 g0 = ((const float4*)gt)[n*M_GT + (m0 & 31)];
        float cf0[4]; coeff_fn(a0, g0, cf0);
        out[n*TOTAL_K + tid] = 0.0f;
        out[(long)N_IMG*TOTAL_K + n*TOTAL_K + tid] = fgdef;
        for(int k=0;k<4;++k)
            out[(long)2*N_IMG*TOTAL_K + ((long)n*TOTAL_K + tid)*4 + k] = cf0[k];
    }
}

extern "C" void kernel_launch(void* const* d_in, const int* in_sizes, int n_in,
                              void* d_out, int out_size, void* d_ws, size_t ws_size,
                              hipStream_t stream){
    const float* anchors = (const float*)d_in[0];  // [36864,4]
    const float* gt      = (const float*)d_in[1];  // [32,32,4]
    const float* dl      = (const float*)d_in[2];  // [32,36864,4]
    const float* rs      = (const float*)d_in[3];  // [32,36864]
    float* out = (float*)d_out;                    // idx[32,256] | fg[32,256] | coeff[32,256,4]
    char* ws = (char*)d_ws;
    size_t off = 0;
    int* flagsA   = (int*)(ws + off); off += (size_t)N_IMG*A_TOT*4;        // 4,718,592
    int* bmax     = (int*)(ws + off); off += (size_t)N_IMG*NCHM*M_GT*4;    // 196,608
    int* pgm      = (int*)(ws + off); off += 4096;                         // NOT zeroed (atomicMax over poison)
    int* hist     = (int*)(ws + off); off += (size_t)N_IMG*2048*4;         // 262,144 (memset)
    int* candcnt  = (int*)(ws + off); off += 256;                          // 64 ints (memset w/ hist)
    int* q        = (int*)(ws + off); off += 512;
    unsigned long long* cand = (unsigned long long*)(ws + off); off += (size_t)N_IMG*2*CAP*8;
    int* chunkcnt = (int*)(ws + off); off += (size_t)N_IMG*NCHUNK*4;

    hipMemsetAsync(hist, 0, (size_t)N_IMG*2048*4 + 256, stream);   // hist | candcnt
    hipLaunchKernelGGL(k_main,  dim3(N_IMG*NCHM),   dim3(256), 0, stream,
                       anchors, gt, dl, rs, bmax, flagsA, pgm, hist);
    hipLaunchKernelGGL(k_fix,   dim3(N_IMG*M_GT),   dim3(256), 0, stream,
                       anchors, gt, dl, bmax, pgm, flagsA, hist);
    hipLaunchKernelGGL(k_quota, dim3(N_IMG),        dim3(256), 0, stream,
                       hist, q);
    hipLaunchKernelGGL(k_bound, dim3(N_IMG*NCHUNK), dim3(256), 0, stream,
                       flagsA, rs, q, cand, candcnt, chunkcnt);
    hipLaunchKernelGGL(k_out,   dim3(N_IMG*NCHUNK), dim3(256), 0, stream,
                       anchors, gt, flagsA, q, candcnt, cand, chunkcnt, out);
}

// Round 8
// 141.417 us; speedup vs baseline: 1.4289x; 1.4289x over previous
//
#include <hip/hip_runtime.h>
#include <math.h>

#define A_TOT  36864
#define N_IMG  32
#define M_GT   32
#define TOTAL_K 256
#define MAX_FG_K 128
#define NCHUNK 144          // 256-anchor chunks per image (tail kernels)
#define NCHM   48           // k_main chunks: 768 contiguous anchors, 3 per thread
#define APB    768
#define CAP    1024
#define FGB    32
#define BGB    64
#define RAW_NEG1 ((int)0xBF800000u)   // __float_as_int(-1.0f)
#define RAW_P07  ((int)0x3F333333u)   // __float_as_int(0.7f)
#define RAW_P03  ((int)0x3E99999Au)   // __float_as_int(0.3f)
#define INT_MINV ((int)0x80000000u)
// IoU values live in {-1.0} ∪ [0,1]; signed-int compare of raw float bits ==
// float compare on that domain (no -0.0/NaN on the valid path).
// flags layout: bid[0:4] | fg<<5 | bg<<6 | bin<<7 (10b)
//
// Shape lessons (R2-R7, all HW-measured):
//  - k_main fast form = STAGGERED-m unrolled loop (R0/R2/R6: 45-49us, VGPR
//    16-28, VALU 71-87%). Uniform-j is 2.3x SLOWER both times tried (R5 100us,
//    R7 107us, VGPR 44-64): compiler clusters the 32 compile-time-offset LDS
//    reads (VGPR x2.3) and the 64-lane same-address atomicMax serializes in
//    the in-order DS queue, landing on the critical path via lgkmcnt waits.
//    Staggered-m spreads atomics over 32 banks (2 lanes each = free, PMC 0).
//  - while(mask)/cull variants serialize on dependent LDS reads: 3x loss.
//  - 1536 blocks * 4 waves = 6144 = 0.75 * 8192 resident-wave capacity ->
//    single dispatch round (R5 lesson, partial).
//  - empty-box clamp + merged vm>0 atomic validated bit-exact (R5/R6 absmax 0).
//  - ~57us graph overhead is FIXED and node-count-independent; tiny extra
//    dispatches are free (R7's k_quota split: tail 42.8 -> 37.5us measured).

__device__ __forceinline__ int bin_of(float r){
    int b = (int)(r * 1024.0f);
    return b > 1023 ? 1023 : (b < 0 ? 0 : b);
}

struct Pred { float x1,y1,x2,y2,area; int valid; };

__device__ __forceinline__ Pred mk_pred(float4 a, float4 d){
#pragma clang fp contract(off)
    Pred p;
    float w  = a.z - a.x + 1.0f;
    float h  = a.w - a.y + 1.0f;
    float cx = a.x + 0.5f*w;
    float cy = a.y + 0.5f*h;
    float pcx = d.x*w + cx;
    float pcy = d.y*h + cy;
    float pw = (float)exp((double)d.z) * w;
    float ph = (float)exp((double)d.w) * h;
    p.x1 = pcx - 0.5f*pw;
    p.y1 = pcy - 0.5f*ph;
    p.x2 = pcx + 0.5f*pw;
    p.y2 = pcy + 0.5f*ph;
    p.valid = (p.x1 >= 0.0f) && (p.y1 >= 0.0f) && (p.x2 < 1024.0f) && (p.y2 < 1024.0f);
    p.area  = (p.x2 - p.x1 + 1.0f) * (p.y2 - p.y1 + 1.0f);
    return p;
}

__device__ __forceinline__ float gt_area(float4 g){
#pragma clang fp contract(off)
    return (g.z - g.x + 1.0f) * (g.w - g.y + 1.0f);
}

__device__ __forceinline__ float iou_val(const Pred& p, float gx1, float gy1,
                                         float gx2, float gy2, float ga){
#pragma clang fp contract(off)
    float iw = fminf(p.x2,gx2) - fmaxf(p.x1,gx1) + 1.0f; iw = iw < 0.0f ? 0.0f : iw;
    float ih = fminf(p.y2,gy2) - fmaxf(p.y1,gy1) + 1.0f; ih = ih < 0.0f ? 0.0f : ih;
    float inter = iw * ih;
    float uni = (p.area + ga) - inter;
    float v = inter / uni;
    return p.valid ? v : -1.0f;
}

__device__ __forceinline__ void coeff_fn(float4 a, float4 g, float cf[4]){
#pragma clang fp contract(off)
    float aw = a.z - a.x + 1.0f, ah = a.w - a.y + 1.0f;
    float acx = a.x + 0.5f*aw,  acy = a.y + 0.5f*ah;
    float gw = g.z - g.x + 1.0f, gh = g.w - g.y + 1.0f;
    float gcx = g.x + 0.5f*gw,  gcy = g.y + 0.5f*gh;
    cf[0] = (gcx - acx) / aw;
    cf[1] = (gcy - acy) / ah;
    cf[2] = (float)log((double)(gw / aw));
    cf[3] = (float)log((double)(gh / ah));
}

// ---------- K1: heavy pass, 3 anchors/thread, staggered-m unrolled loop.
// ---------- BYTE-IDENTICAL to R6's measured-45.0us kernel. ------------------
__global__ __launch_bounds__(256) void k_main(
        const float* __restrict__ anchors, const float* __restrict__ gt,
        const float* __restrict__ dl, const float* __restrict__ rs,
        int* __restrict__ bmax, int* __restrict__ flagsA,
        int* __restrict__ pgm, int* __restrict__ hist){
#pragma clang fp contract(off)
    int blk = blockIdx.x;
    int n = blk / NCHM, ch = blk % NCHM;
    int tid = threadIdx.x;
    __shared__ float4 sgt[M_GT];
    __shared__ float  sga[M_GT];
    __shared__ int    sbm[M_GT];
    if(tid < M_GT){
        float4 g = ((const float4*)gt)[n*M_GT + tid];
        sgt[tid] = g; sga[tid] = gt_area(g); sbm[tid] = RAW_NEG1;
    }
    __syncthreads();
    int a0 = ch*APB + tid;
    long ia0 = (long)n*A_TOT + a0;
    float4 anc0 = ((const float4*)anchors)[a0];
    float4 anc1 = ((const float4*)anchors)[a0 + 256];
    float4 anc2 = ((const float4*)anchors)[a0 + 512];
    float4 d0   = ((const float4*)dl)[ia0];
    float4 d1   = ((const float4*)dl)[ia0 + 256];
    float4 d2   = ((const float4*)dl)[ia0 + 512];
    Pred p0 = mk_pred(anc0, d0);
    Pred p1 = mk_pred(anc1, d1);
    Pred p2 = mk_pred(anc2, d2);
    // empty-box clamp (validated R5/R6, absmax 0): invalid => iw<0 => v=+0.0
    // exactly for every gt; downstream outcomes identical to -1 convention.
    if(!p0.valid){ p0.x1 = 2.0e9f; p0.x2 = -2.0e9f; }
    if(!p1.valid){ p1.x1 = 2.0e9f; p1.x2 = -2.0e9f; }
    if(!p2.valid){ p2.x1 = 2.0e9f; p2.x2 = -2.0e9f; }
    int beste0 = INT_MINV, bid0 = 0;
    int beste1 = INT_MINV, bid1 = 0;
    int beste2 = INT_MINV, bid2 = 0;
    int mm0 = tid & 31;
    #pragma unroll
    for(int j=0;j<M_GT;++j){
        int m = (mm0 + j) & 31;               // stagger: 2-way same-addr atomic (free)
        float4 g = sgt[m];
        float ga = sga[m];
        float iw0 = fminf(p0.x2,g.z) - fmaxf(p0.x1,g.x) + 1.0f; iw0 = iw0 < 0.0f ? 0.0f : iw0;
        float ih0 = fminf(p0.y2,g.w) - fmaxf(p0.y1,g.y) + 1.0f; ih0 = ih0 < 0.0f ? 0.0f : ih0;
        float in0 = iw0 * ih0;
        int vi0 = __float_as_int(in0 / ((p0.area + ga) - in0));
        float iw1 = fminf(p1.x2,g.z) - fmaxf(p1.x1,g.x) + 1.0f; iw1 = iw1 < 0.0f ? 0.0f : iw1;
        float ih1 = fminf(p1.y2,g.w) - fmaxf(p1.y1,g.y) + 1.0f; ih1 = ih1 < 0.0f ? 0.0f : ih1;
        float in1 = iw1 * ih1;
        int vi1 = __float_as_int(in1 / ((p1.area + ga) - in1));
        float iw2 = fminf(p2.x2,g.z) - fmaxf(p2.x1,g.x) + 1.0f; iw2 = iw2 < 0.0f ? 0.0f : iw2;
        float ih2 = fminf(p2.y2,g.w) - fmaxf(p2.y1,g.y) + 1.0f; ih2 = ih2 < 0.0f ? 0.0f : ih2;
        float in2 = iw2 * ih2;
        int vi2 = __float_as_int(in2 / ((p2.area + ga) - in2));
        int vm01 = vi0 > vi1 ? vi0 : vi1;
        int vm = vm01 > vi2 ? vm01 : vi2;
        if(vm > 0) atomicMax(&sbm[m], vm);    // validated filter (R2/R5)
        // rotated visit order => explicit (v desc, m asc) tie-break == first argmax
        if(vi0 > beste0 || (vi0 == beste0 && m < bid0)){ beste0 = vi0; bid0 = m; }
        if(vi1 > beste1 || (vi1 == beste1 && m < bid1)){ beste1 = vi1; bid1 = m; }
        if(vi2 > beste2 || (vi2 == beste2 && m < bid2)){ beste2 = vi2; bid2 = m; }
    }
    int bin0 = bin_of(rs[ia0]);
    int bin1 = bin_of(rs[ia0 + 256]);
    int bin2 = bin_of(rs[ia0 + 512]);
    int thrfg0 = (beste0 >= RAW_P07) ? 1 : 0;
    int thrfg1 = (beste1 >= RAW_P07) ? 1 : 0;
    int thrfg2 = (beste2 >= RAW_P07) ? 1 : 0;
    int bg0 = (!thrfg0) & (beste0 < RAW_P03 ? 1 : 0) & p0.valid;
    int bg1 = (!thrfg1) & (beste1 < RAW_P03 ? 1 : 0) & p1.valid;
    int bg2 = (!thrfg2) & (beste2 < RAW_P03 ? 1 : 0) & p2.valid;
    flagsA[ia0]       = bid0 | (thrfg0<<5) | (bg0<<6) | (bin0<<7);
    flagsA[ia0 + 256] = bid1 | (thrfg1<<5) | (bg1<<6) | (bin1<<7);
    flagsA[ia0 + 512] = bid2 | (thrfg2<<5) | (bg2<<6) | (bin2<<7);
    if(thrfg0 | bg0) atomicAdd(&hist[n*2048 + (thrfg0?0:1024) + bin0], 1);
    if(thrfg1 | bg1) atomicAdd(&hist[n*2048 + (thrfg1?0:1024) + bin1], 1);
    if(thrfg2 | bg2) atomicAdd(&hist[n*2048 + (thrfg2?0:1024) + bin2], 1);
    __syncthreads();
    if(tid < M_GT){
        bmax[blk*M_GT + tid] = sbm[tid];
        atomicMax(&pgm[n*M_GT + tid], sbm[tid]);   // poison 0xAAAAAAAA < raw(-1): no init needed
    }
}

// ---------- K2: sparse abox fix (R6 verbatim). ------------------------------
__global__ void k_fix(const float* __restrict__ anchors, const float* __restrict__ gt,
                      const float* __restrict__ dl, const int* __restrict__ bmax,
                      const int* __restrict__ pgm, int* __restrict__ flagsA,
                      int* __restrict__ hist){
    int n = blockIdx.x >> 5, m = blockIdx.x & 31;
    int tid = threadIdx.x;
    int target = pgm[n*M_GT + m];
    float4 g = ((const float4*)gt)[n*M_GT + m];
    float ga = gt_area(g);
    __shared__ int s_hits[NCHM];
    __shared__ int s_nh;
    if(tid==0) s_nh = 0;
    __syncthreads();
    if(tid < NCHM && bmax[(n*NCHM + tid)*M_GT + m] == target){
        int pos = atomicAdd(&s_nh, 1);
        s_hits[pos] = tid;
    }
    __syncthreads();
    int nh = s_nh;
    for(int h=0; h<nh; ++h){
        int ch = s_hits[h];
        for(int t=tid; t<APB; t+=256){
            int a = ch*APB + t;
            long ia = (long)n*A_TOT + a;
            float4 anc = ((const float4*)anchors)[a];
            float4 d   = ((const float4*)dl)[ia];
            Pred p = mk_pred(anc, d);
            float v = iou_val(p, g.x, g.y, g.z, g.w, ga);
            if(p.valid && __float_as_int(v) == target){
                int old = atomicOr(&flagsA[ia], FGB);
                if(!(old & FGB)){                 // fg transition: repair histogram
                    int bin = (old >> 7) & 1023;
                    atomicAdd(&hist[n*2048 + bin], 1);
                    if(old & BGB) atomicSub(&hist[n*2048 + 1024 + bin], 1);
                }
            }
        }
    }
}

// ---------- K2b: quota once per image (R7 verbatim; tail 42.8->37.5us). -----
__global__ __launch_bounds__(256) void k_quota(const int* __restrict__ hist,
                                               int* __restrict__ q){
    int n = blockIdx.x, tid = threadIdx.x;
    __shared__ int s_scan[256];
    __shared__ int s_q[4];
    int fgK = 0;
    for(int phase=0; phase<2; ++phase){
        int b0 = 1023 - 4*tid;                              // bins b0..b0-3 desc
        int4 h4 = *(const int4*)&hist[n*2048 + phase*1024 + b0 - 3];
        int part = h4.x + h4.y + h4.z + h4.w;
        s_scan[tid] = part;
        __syncthreads();
        for(int off=1; off<256; off<<=1){
            int add = (tid>=off) ? s_scan[tid-off] : 0;
            __syncthreads();
            s_scan[tid] += add;
            __syncthreads();
        }
        int total = s_scan[255];
        if(tid==0){ s_q[phase*2] = -1; s_q[phase*2+1] = 0; }
        __syncthreads();
        int quota = (phase==0) ? MAX_FG_K : (TOTAL_K - fgK);
        if(total > quota){
            int pre = s_scan[tid] - part, cum = pre;
            int hs4[4] = {h4.w, h4.z, h4.y, h4.x};          // descending bin order
            for(int j=0;j<4;++j){
                int hh = hs4[j];
                if(cum < quota && cum + hh >= quota){ s_q[phase*2] = b0-j; s_q[phase*2+1] = quota-cum; }
                cum += hh;
            }
        }
        __syncthreads();
        if(phase==0) fgK = (total < MAX_FG_K) ? total : MAX_FG_K;
    }
    if(tid < 4) q[n*4 + tid] = s_q[tid];
}

// ---------- K3: sure-keeps, boundary candidates, chunk counts (R7 verbatim). -
__global__ void k_bound(const int* __restrict__ flagsA, const float* __restrict__ rs,
                        const int* __restrict__ q,
                        unsigned long long* __restrict__ cand, int* __restrict__ candcnt,
                        int* __restrict__ chunkcnt){
    int blk = blockIdx.x, tid = threadIdx.x;
    int n = blk / NCHUNK, ch = blk % NCHUNK;
    int wave = tid >> 6, lane = tid & 63;
    __shared__ int s_wc[4];
    int bs0 = q[n*4+0], bs1 = q[n*4+2];
    int a = ch*256 + tid;
    long ia = (long)n*A_TOT + a;
    int f = flagsA[ia];
    int fg = (f>>5)&1;
    int bg = ((f>>6)&1) & !fg;
    int bin = (f>>7)&1023;
    int sure = 0;
    if(fg | bg){
        int c = fg ? 0 : 1;
        int bsel = fg ? bs0 : bs1;
        if(bin > bsel) sure = 1;                 // keepAll encoded as bsel=-1
        else if(bin == bsel){
            int pos = atomicAdd(&candcnt[n*2+c], 1);
            if(pos < CAP){
                // key: (r desc, index asc); r>=0 so raw bits order as uint
                cand[(n*2+c)*CAP + pos] =
                    (((unsigned long long)__float_as_uint(rs[ia]))<<32) | (unsigned)(A_TOT - a);
            }
        }
    }
    unsigned long long mk = __ballot(sure);
    if(lane==0) s_wc[wave] = __popcll(mk);
    __syncthreads();
    if(tid==0) chunkcnt[n*NCHUNK + ch] = s_wc[0]+s_wc[1]+s_wc[2]+s_wc[3];
}

// ---------- K4: merged rank+emit (R7 verbatim). -----------------------------
__global__ __launch_bounds__(256) void k_out(const float* __restrict__ anchors,
        const float* __restrict__ gt, const int* __restrict__ flagsA,
        const int* __restrict__ q, const int* __restrict__ candcnt,
        const unsigned long long* __restrict__ cand,
        const int* __restrict__ chunkcnt, float* __restrict__ out){
    int blk = blockIdx.x, tid = threadIdx.x;
    int n = blk / NCHUNK, ch = blk % NCHUNK;
    int wave = tid >> 6, lane = tid & 63;
    __shared__ unsigned long long s_ckey[CAP];   // 8 KB, reused per class
    __shared__ int s_scan[256];
    __shared__ int s_cex[NCHUNK];                // rank-keep extras per chunk
    __shared__ unsigned int s_keep[8];           // own-chunk keep bits
    __shared__ int s_wc[4];
    for(int i=tid; i<NCHUNK; i+=256) s_cex[i] = 0;
    if(tid < 8) s_keep[tid] = 0u;
    int bs0 = q[n*4+0], bs1 = q[n*4+2];
    int tk[2] = { q[n*4+1], q[n*4+3] };
    __syncthreads();
    // ---- redundant rank of boundary candidates (deterministic: same data) ----
    for(int c=0; c<2; ++c){
        int take = tk[c];
        if(take == 0) continue;                  // no boundary => no candidates used
        int cc = candcnt[n*2+c]; if(cc > CAP) cc = CAP;
        for(int i=tid; i<cc; i+=256) s_ckey[i] = cand[(n*2+c)*CAP + i];
        __syncthreads();
        for(int i=tid; i<cc; i+=256){
            unsigned long long ki = s_ckey[i];
            int rank = 0;
            for(int j=0;j<cc;++j) rank += (s_ckey[j] > ki) ? 1 : 0;
            if(rank < take){
                int ai = A_TOT - (int)(ki & 0xffffffffu);
                atomicAdd(&s_cex[ai>>8], 1);
                if((ai>>8) == ch) atomicOr(&s_keep[(ai&255)>>5], 1u << (ai & 31));
            }
        }
        __syncthreads();
    }
    // ---- chunk-base prefix (144 L2-hot ints + LDS extras) ----
    int v = (tid < NCHUNK) ? chunkcnt[n*NCHUNK + tid] + s_cex[tid] : 0;
    s_scan[tid] = v;
    __syncthreads();
    for(int off=1; off<256; off<<=1){
        int add = (tid>=off) ? s_scan[tid-off] : 0;
        __syncthreads();
        s_scan[tid] += add;
        __syncthreads();
    }
    int T = s_scan[255];                          // total kept (<= 256)
    int base = (ch > 0) ? s_scan[ch-1] : 0;
    // ---- emit own chunk ----
    int a = ch*256 + tid;
    long ia = (long)n*A_TOT + a;
    int f = flagsA[ia];
    int fg = (f>>5)&1;
    int bg = ((f>>6)&1) & !fg;
    int bin = (f>>7)&1023;
    int bit = (int)((s_keep[tid>>5] >> (tid&31)) & 1u);
    int kept = 0;
    if(fg)      kept = (bin > bs0) || bit;
    else if(bg) kept = (bin > bs1) || bit;
    unsigned long long mk = __ballot(kept);
    if(lane==0) s_wc[wave] = __popcll(mk);
    __syncthreads();
    if(kept){
        int slot = base;
        for(int w=0; w<wave; ++w) slot += s_wc[w];
        slot += __popcll(mk & ((1ull<<lane)-1ull));
        if(slot < TOTAL_K){
            out[n*TOTAL_K + slot] = (float)a;
            out[(long)N_IMG*TOTAL_K + n*TOTAL_K + slot] = fg ? 1.0f : 0.0f;
            float4 aa = ((const float4*)anchors)[a];
            float4 gg = ((const float4*)gt)[n*M_GT + (f & 31)];
            float cf[4]; coeff_fn(aa, gg, cf);
            for(int k=0;k<4;++k)
                out[(long)2*N_IMG*TOTAL_K + ((long)n*TOTAL_K + slot)*4 + k] = cf[k];
        }
    }
    // ---- defaults: padding slots [T,256) behave like anchor 0 (reference
    // ---- zero-init scatter). Disjoint from all emission slots (<T). ----
    if(ch == 0 && tid >= T){
        int m0 = flagsA[(long)n*A_TOT];           // post-fix (no flag writes here)
        int fg0 = (m0>>5)&1, bin0 = (m0>>7)&1023;
        int k0b = (int)(s_keep[0] & 1u);          // only matters when fg0 set
        float fgdef = (fg0 && ((bin0 > bs0) || k0b)) ? 1.0f : 0.0f;
        float4 a0 = ((const float4*)anchors)[0];
        float4 g0 = ((const float4*)gt)[n*M_GT + (m0 & 31)];
        float cf0[4]; coeff_fn(a0, g0, cf0);
        out[n*TOTAL_K + tid] = 0.0f;
        out[(long)N_IMG*TOTAL_K + n*TOTAL_K + tid] = fgdef;
        for(int k=0;k<4;++k)
            out[(long)2*N_IMG*TOTAL_K + ((long)n*TOTAL_K + tid)*4 + k] = cf0[k];
    }
}

extern "C" void kernel_launch(void* const* d_in, const int* in_sizes, int n_in,
                              void* d_out, int out_size, void* d_ws, size_t ws_size,
                              hipStream_t stream){
    const float* anchors = (const float*)d_in[0];  // [36864,4]
    const float* gt      = (const float*)d_in[1];  // [32,32,4]
    const float* dl      = (const float*)d_in[2];  // [32,36864,4]
    const float* rs      = (const float*)d_in[3];  // [32,36864]
    float* out = (float*)d_out;                    // idx[32,256] | fg[32,256] | coeff[32,256,4]
    char* ws = (char*)d_ws;
    size_t off = 0;
    int* flagsA   = (int*)(ws + off); off += (size_t)N_IMG*A_TOT*4;        // 4,718,592
    int* bmax     = (int*)(ws + off); off += (size_t)N_IMG*NCHM*M_GT*4;    // 196,608
    int* pgm      = (int*)(ws + off); off += 4096;                         // NOT zeroed (atomicMax over poison)
    int* hist     = (int*)(ws + off); off += (size_t)N_IMG*2048*4;         // 262,144 (memset)
    int* candcnt  = (int*)(ws + off); off += 256;                          // 64 ints (memset w/ hist)
    int* q        = (int*)(ws + off); off += 512;
    unsigned long long* cand = (unsigned long long*)(ws + off); off += (size_t)N_IMG*2*CAP*8;
    int* chunkcnt = (int*)(ws + off); off += (size_t)N_IMG*NCHUNK*4;

    hipMemsetAsync(hist, 0, (size_t)N_IMG*2048*4 + 256, stream);   // hist | candcnt
    hipLaunchKernelGGL(k_main,  dim3(N_IMG*NCHM),   dim3(256), 0, stream,
                       anchors, gt, dl, rs, bmax, flagsA, pgm, hist);
    hipLaunchKernelGGL(k_fix,   dim3(N_IMG*M_GT),   dim3(256), 0, stream,
                       anchors, gt, dl, bmax, pgm, flagsA, hist);
    hipLaunchKernelGGL(k_quota, dim3(N_IMG),        dim3(256), 0, stream,
                       hist, q);
    hipLaunchKernelGGL(k_bound, dim3(N_IMG*NCHUNK), dim3(256), 0, stream,
                       flagsA, rs, q, cand, candcnt, chunkcnt);
    hipLaunchKernelGGL(k_out,   dim3(N_IMG*NCHUNK), dim3(256), 0, stream,
                       anchors, gt, flagsA, q, candcnt, cand, chunkcnt, out);
}